// Round 6
// baseline (148.879 us; speedup 1.0000x reference)
//
#include <hip/hip_runtime.h>
#include <hip/hip_bf16.h>
#include <stdint.h>

// B=16, T=2048, E=1024, H=128
typedef __attribute__((ext_vector_type(8))) short bf16x8;
typedef __attribute__((ext_vector_type(16))) float f32x16;
typedef __attribute__((ext_vector_type(4))) float f32x4;

__device__ __forceinline__ uint32_t cvt_pk_bf16(float a, float b){
  uint32_t r;
  asm volatile("v_cvt_pk_bf16_f32 %0, %1, %2" : "=v"(r) : "v"(a), "v"(b));
  return r;
}
__device__ __forceinline__ void permswap32(uint32_t &a, uint32_t &b){
  asm volatile("v_permlane32_swap_b32 %0, %1" : "+v"(a), "+v"(b));
}
__device__ __forceinline__ unsigned short f2bf(float f){
  uint32_t u = __float_as_uint(f);
  u += 0x7fff + ((u >> 16) & 1);   // RNE
  return (unsigned short)(u >> 16);
}

// Layouts:
//  Wt fragment-major: B-frag (16 cols x 32 k) = 512 elems contiguous.
//    elem(n,k) -> ((k>>5)*24 + (n>>4))*512 + (n&15)*32 + (k&31);  n = mat*128+h, k = e.
//    (24 n-fragments per k-slice: 384/16 = 24.)
//  QK: elem(b,t,h) -> (b*64 + t/32)*4096 + (h/16)*512 + (t%32)*16 + (h%16)
//  V : elem(b,s,h) -> ((b*64 + s/32)*4 + h/32)*1024 + ((s/16)%2)*512 + (h%32)*16 + (s%16)

// ---------------- Kernel 1: W -> Wt bf16 fragment-major (write-coalesced)
__global__ void prep_w(const float* __restrict__ Wk, const float* __restrict__ Wq,
                       const float* __restrict__ Wv, unsigned short* __restrict__ Wt){
  int idx = blockIdx.x * 256 + threadIdx.x;       // 0 .. 393215  (= dest address)
  int fid = idx >> 9;          // fragment id = (k>>5)*24 + (n>>4), 0..767
  int within = idx & 511;
  int nlo = within >> 5;       // n & 15
  int elo = within & 31;       // k & 31
  int kq = fid / 24;           // 0..31
  int nq = fid - kq * 24;      // 0..23
  int n  = nq * 16 + nlo;      // 0..383
  int e  = kq * 32 + elo;      // 0..1023
  int mat = n >> 7;
  int h   = n & 127;
  const float* src = (mat == 0) ? Wq : (mat == 1) ? Wk : Wv;
  float v = src[e * 128 + h];
  if (mat == 0) v *= (1.4426950408889634f * 0.08838834764831845f); // log2e/sqrt(128)
  Wt[idx] = f2bf(v);
}

// ---------------- Kernel 2: fused QKV projection GEMM, LDS-free.
// BM=32, BN=384 (wave -> 96 cols), BK=32. Operands direct from global (L2-resident
// fragment-major Wt; x as 2xfloat4/lane), register prefetch one k-step ahead.
__global__ __launch_bounds__(256, 3) void proj_gemm(
    const float* __restrict__ x, const unsigned short* __restrict__ Wt,
    unsigned short* __restrict__ Qb, unsigned short* __restrict__ Kb,
    unsigned short* __restrict__ Vt){
  const int tid  = threadIdx.x;
  const int lane = tid & 63;
  const int w    = tid >> 6;        // wave 0..3 = column group (96 cols each)
  const int lr   = lane & 15;
  const int lk   = lane >> 4;       // 0..3
  const int m0   = blockIdx.x * 32; // token-tile base (flat M=32768)

  f32x4 acc[2][6];
  #pragma unroll
  for (int i = 0; i < 2; ++i)
    #pragma unroll
    for (int jj = 0; jj < 6; ++jj) acc[i][jj] = (f32x4){0.f, 0.f, 0.f, 0.f};

  // per-lane bases
  const float* xp = x + (size_t)(m0 + lr) * 1024 + lk * 8;          // + am*16*1024 + ks*32
  const unsigned short* bp = Wt + lr * 32 + lk * 8;                 // + fragid*512

  union BU { uint32_t u[4]; bf16x8 v; };

  // current operands
  bf16x8 af0, af1, bcur0, bcur1, bcur2, bcur3, bcur4, bcur5;
  // prologue: load ks=0
  {
    float4 a00 = *(const float4*)(xp);
    float4 a01 = *(const float4*)(xp + 4);
    float4 a10 = *(const float4*)(xp + 16 * 1024);
    float4 a11 = *(const float4*)(xp + 16 * 1024 + 4);
    const unsigned short* bk = bp + (size_t)(w * 6) * 512;
    bcur0 = *(const bf16x8*)(bk + 0 * 512);
    bcur1 = *(const bf16x8*)(bk + 1 * 512);
    bcur2 = *(const bf16x8*)(bk + 2 * 512);
    bcur3 = *(const bf16x8*)(bk + 3 * 512);
    bcur4 = *(const bf16x8*)(bk + 4 * 512);
    bcur5 = *(const bf16x8*)(bk + 5 * 512);
    BU u0; u0.u[0] = cvt_pk_bf16(a00.x, a00.y); u0.u[1] = cvt_pk_bf16(a00.z, a00.w);
           u0.u[2] = cvt_pk_bf16(a01.x, a01.y); u0.u[3] = cvt_pk_bf16(a01.z, a01.w);
    af0 = u0.v;
    BU u1; u1.u[0] = cvt_pk_bf16(a10.x, a10.y); u1.u[1] = cvt_pk_bf16(a10.z, a10.w);
           u1.u[2] = cvt_pk_bf16(a11.x, a11.y); u1.u[3] = cvt_pk_bf16(a11.z, a11.w);
    af1 = u1.v;
  }

  for (int ks = 0; ks < 32; ++ks){
    float4 a00, a01, a10, a11;
    bf16x8 bn0, bn1, bn2, bn3, bn4, bn5;
    const bool more = (ks + 1) < 32;
    if (more){
      const float* xk = xp + (ks + 1) * 32;
      a00 = *(const float4*)(xk);
      a01 = *(const float4*)(xk + 4);
      a10 = *(const float4*)(xk + 16 * 1024);
      a11 = *(const float4*)(xk + 16 * 1024 + 4);
      const unsigned short* bk = bp + (size_t)((ks + 1) * 24 + w * 6) * 512;
      bn0 = *(const bf16x8*)(bk + 0 * 512);
      bn1 = *(const bf16x8*)(bk + 1 * 512);
      bn2 = *(const bf16x8*)(bk + 2 * 512);
      bn3 = *(const bf16x8*)(bk + 3 * 512);
      bn4 = *(const bf16x8*)(bk + 4 * 512);
      bn5 = *(const bf16x8*)(bk + 5 * 512);
    }
    // 12 independent MFMAs on current operands
    acc[0][0] = __builtin_amdgcn_mfma_f32_16x16x32_bf16(af0, bcur0, acc[0][0], 0, 0, 0);
    acc[1][0] = __builtin_amdgcn_mfma_f32_16x16x32_bf16(af1, bcur0, acc[1][0], 0, 0, 0);
    acc[0][1] = __builtin_amdgcn_mfma_f32_16x16x32_bf16(af0, bcur1, acc[0][1], 0, 0, 0);
    acc[1][1] = __builtin_amdgcn_mfma_f32_16x16x32_bf16(af1, bcur1, acc[1][1], 0, 0, 0);
    acc[0][2] = __builtin_amdgcn_mfma_f32_16x16x32_bf16(af0, bcur2, acc[0][2], 0, 0, 0);
    acc[1][2] = __builtin_amdgcn_mfma_f32_16x16x32_bf16(af1, bcur2, acc[1][2], 0, 0, 0);
    acc[0][3] = __builtin_amdgcn_mfma_f32_16x16x32_bf16(af0, bcur3, acc[0][3], 0, 0, 0);
    acc[1][3] = __builtin_amdgcn_mfma_f32_16x16x32_bf16(af1, bcur3, acc[1][3], 0, 0, 0);
    acc[0][4] = __builtin_amdgcn_mfma_f32_16x16x32_bf16(af0, bcur4, acc[0][4], 0, 0, 0);
    acc[1][4] = __builtin_amdgcn_mfma_f32_16x16x32_bf16(af1, bcur4, acc[1][4], 0, 0, 0);
    acc[0][5] = __builtin_amdgcn_mfma_f32_16x16x32_bf16(af0, bcur5, acc[0][5], 0, 0, 0);
    acc[1][5] = __builtin_amdgcn_mfma_f32_16x16x32_bf16(af1, bcur5, acc[1][5], 0, 0, 0);
    if (more){
      BU u0; u0.u[0] = cvt_pk_bf16(a00.x, a00.y); u0.u[1] = cvt_pk_bf16(a00.z, a00.w);
             u0.u[2] = cvt_pk_bf16(a01.x, a01.y); u0.u[3] = cvt_pk_bf16(a01.z, a01.w);
      af0 = u0.v;
      BU u1; u1.u[0] = cvt_pk_bf16(a10.x, a10.y); u1.u[1] = cvt_pk_bf16(a10.z, a10.w);
             u1.u[2] = cvt_pk_bf16(a11.x, a11.y); u1.u[3] = cvt_pk_bf16(a11.z, a11.w);
      af1 = u1.v;
      bcur0 = bn0; bcur1 = bn1; bcur2 = bn2; bcur3 = bn3; bcur4 = bn4; bcur5 = bn5;
    }
  }

  const int b  = m0 >> 11;
  const int t0 = m0 & 2047;
  #pragma unroll
  for (int am = 0; am < 2; ++am){
    #pragma unroll
    for (int bn = 0; bn < 6; ++bn){
      int c0   = w * 96 + bn * 16;
      int mat  = c0 >> 7;
      int hcol = (c0 & 127) + lr;
      int tr   = t0 + am * 16 + lk * 4;    // D: row=(lane>>4)*4+j, col=lane&15
      f32x4 v = acc[am][bn];
      if (mat <= 1){
        unsigned short* dst = (mat == 0) ? Qb : Kb;
        // fragment-major QK store
        size_t base = (size_t)(b * 64 + (tr >> 5)) * 4096 + (size_t)(hcol >> 4) * 512 + (hcol & 15);
        #pragma unroll
        for (int jj = 0; jj < 4; ++jj)
          dst[base + (size_t)((tr + jj) & 31) * 16] = f2bf(v[jj]);
      } else { // V fragment-major: 4 consecutive s -> 8B store
        ushort4 pk;
        pk.x = f2bf(v[0]); pk.y = f2bf(v[1]); pk.z = f2bf(v[2]); pk.w = f2bf(v[3]);
        size_t addr = (size_t)((b * 64 + (tr >> 5)) * 4 + (hcol >> 5)) * 1024
                    + (size_t)((tr >> 4) & 1) * 512 + (size_t)(hcol & 31) * 16 + (tr & 15);
        *(ushort4*)(Vt + addr) = pk;
      }
    }
  }
}

// ---------------- Kernel 3: causal flash attention, swapped-QK 32x32x16.
// 1024 blocks, 4 waves = 4-way kv split, scale-then-sum combine (17.9KB LDS).
__global__ __launch_bounds__(256, 2) void attn(
    const unsigned short* __restrict__ Qf, const unsigned short* __restrict__ Kf,
    const unsigned short* __restrict__ Vf, float* __restrict__ out){
  __shared__ float comb[32][132];
  __shared__ float msh[4][32];
  __shared__ float lsh[4][32];

  const int tid  = threadIdx.x;
  const int lane = tid & 63;
  const int w    = tid >> 6;            // kv-split index 0..3
  const int bid  = blockIdx.x;
  const int xcd  = bid & 7;
  const int k    = bid >> 3;            // 0..127 within XCD
  const int a    = k & 31;
  const int mdx  = k >> 5;              // 0..3
  const int b    = xcd * 2 + (mdx >> 1);
  const int c    = (mdx & 1) ? a : 63 - a;   // per-CU sets {63-a, a} x 2 batches
  const int r0   = c * 32;
  const int q5   = lane & 31;
  const int hi   = lane >> 5;

  bf16x8 qf[8];
  const unsigned short* qp = Qf + (size_t)(b * 64 + c) * 4096 + q5 * 16 + hi * 8;
  #pragma unroll
  for (int f = 0; f < 8; ++f) qf[f] = *(const bf16x8*)(qp + f * 512);

  f32x16 oacc[4];
  #pragma unroll
  for (int i = 0; i < 4; ++i) oacc[i] = (f32x16)(0.f);
  float m = -1e30f, l = 0.f;

  const unsigned short* kb = Kf + (size_t)b * 64 * 4096;
  const unsigned short* vb = Vf + (size_t)b * 64 * 4096;

  bf16x8 kf[8];
  if (w <= c){
    const unsigned short* kp = kb + (size_t)w * 4096 + q5 * 16 + hi * 8;
    #pragma unroll
    for (int f = 0; f < 8; ++f) kf[f] = *(const bf16x8*)(kp + f * 512);
  }

  for (int t = w; t <= c; t += 4){
    f32x16 sacc = (f32x16)(0.f);   // S^T[s][q] = sum_h K[s][h] Q[q][h]
    #pragma unroll
    for (int f = 0; f < 8; ++f)
      sacc = __builtin_amdgcn_mfma_f32_32x32x16_bf16(kf[f], qf[f], sacc, 0, 0, 0);
    // prefetch next K tile (overlaps softmax+PV)
    if (t + 4 <= c){
      const unsigned short* kp = kb + (size_t)(t + 4) * 4096 + q5 * 16 + hi * 8;
      #pragma unroll
      for (int f = 0; f < 8; ++f) kf[f] = *(const bf16x8*)(kp + f * 512);
    }
    // V fragments (contiguous 1KB per instr), issued before softmax
    bf16x8 vf[8];
    const unsigned short* vp = vb + (size_t)t * 4096 + q5 * 16 + hi * 8;
    #pragma unroll
    for (int ht = 0; ht < 4; ++ht)
      #pragma unroll
      for (int sf = 0; sf < 2; ++sf)
        vf[ht * 2 + sf] = *(const bf16x8*)(vp + ht * 1024 + sf * 512);

    float sv[16];
    #pragma unroll
    for (int r = 0; r < 16; ++r) sv[r] = sacc[r];
    if (t == c){   // diagonal tile: mask s>q  (row = (r&3)+8*(r>>2)+4*hi, col q = q5)
      #pragma unroll
      for (int r = 0; r < 16; ++r){
        int srow = (r & 3) + 8 * (r >> 2) + 4 * hi;
        if (srow > q5) sv[r] = -1e30f;
      }
    }
    float pm = sv[0];
    #pragma unroll
    for (int r = 1; r < 16; ++r) pm = fmaxf(pm, sv[r]);
    pm = fmaxf(pm, __shfl_xor(pm, 32));
    if (!__all(pm - m <= 8.0f)){   // defer-max (log2 domain)
      float mn = fmaxf(m, pm);
      float al = exp2f(m - mn);
      #pragma unroll
      for (int i = 0; i < 4; ++i) oacc[i] *= al;
      l *= al;
      m = mn;
    }
    float pv[16]; float ts = 0.f;
    #pragma unroll
    for (int r = 0; r < 16; ++r){ pv[r] = exp2f(sv[r] - m); ts += pv[r]; }
    ts += __shfl_xor(ts, 32);
    l += ts;
    // P^T -> bf16 B-frags: cvt_pk + permlane32_swap (fills both k-halves)
    uint32_t w0 = cvt_pk_bf16(pv[0],  pv[1]);
    uint32_t w2 = cvt_pk_bf16(pv[4],  pv[5]);  permswap32(w0, w2);
    uint32_t w1 = cvt_pk_bf16(pv[2],  pv[3]);
    uint32_t w3 = cvt_pk_bf16(pv[6],  pv[7]);  permswap32(w1, w3);
    uint32_t w4 = cvt_pk_bf16(pv[8],  pv[9]);
    uint32_t w6 = cvt_pk_bf16(pv[12], pv[13]); permswap32(w4, w6);
    uint32_t w5 = cvt_pk_bf16(pv[10], pv[11]);
    uint32_t w7 = cvt_pk_bf16(pv[14], pv[15]); permswap32(w5, w7);
    union { uint32_t u[4]; bf16x8 v; } pf0u, pf1u;
    pf0u.u[0] = w0; pf0u.u[1] = w1; pf0u.u[2] = w2; pf0u.u[3] = w3;
    pf1u.u[0] = w4; pf1u.u[1] = w5; pf1u.u[2] = w6; pf1u.u[3] = w7;
    #pragma unroll
    for (int ht = 0; ht < 4; ++ht){   // O^T[h][q] += V^T · P^T
      oacc[ht] = __builtin_amdgcn_mfma_f32_32x32x16_bf16(vf[ht * 2 + 0], pf0u.v, oacc[ht], 0, 0, 0);
      oacc[ht] = __builtin_amdgcn_mfma_f32_32x32x16_bf16(vf[ht * 2 + 1], pf1u.v, oacc[ht], 0, 0, 0);
    }
  }

  // -------- scale-then-sum combine --------
  if (hi == 0){ msh[w][q5] = m; lsh[w][q5] = l; }
  __syncthreads();
  {
    float mv0 = msh[0][q5], mv1 = msh[1][q5], mv2 = msh[2][q5], mv3 = msh[3][q5];
    float lv0 = lsh[0][q5], lv1 = lsh[1][q5], lv2 = lsh[2][q5], lv3 = lsh[3][q5];
    float mfm = fmaxf(fmaxf(mv0, mv1), fmaxf(mv2, mv3));
    float lf  = lv0 * exp2f(mv0 - mfm) + lv1 * exp2f(mv1 - mfm)
              + lv2 * exp2f(mv2 - mfm) + lv3 * exp2f(mv3 - mfm);
    float s = exp2f(m - mfm) / lf;
    #pragma unroll
    for (int ht = 0; ht < 4; ++ht) oacc[ht] *= s;
  }
  // serial RMW accumulate into comb (wave 0 writes, 1..3 add)
  #pragma unroll 1
  for (int rr = 0; rr < 4; ++rr){
    if (w == rr){
      #pragma unroll
      for (int ht = 0; ht < 4; ++ht)
        #pragma unroll
        for (int r4 = 0; r4 < 4; ++r4){
          int hh = ht * 32 + 8 * r4 + 4 * hi;
          float4 add;
          add.x = oacc[ht][r4 * 4 + 0]; add.y = oacc[ht][r4 * 4 + 1];
          add.z = oacc[ht][r4 * 4 + 2]; add.w = oacc[ht][r4 * 4 + 3];
          float* p = &comb[q5][hh];
          if (rr == 0) *(float4*)p = add;
          else { float4 cur = *(const float4*)p;
                 cur.x += add.x; cur.y += add.y; cur.z += add.z; cur.w += add.w;
                 *(float4*)p = cur; }
        }
    }
    __syncthreads();
  }
  // cooperative coalesced store: 32 rows x 128 f32
  float* obase = out + ((size_t)b * 2048 + r0) * 128;
  #pragma unroll
  for (int it = 0; it < 4; ++it){
    int row = it * 8 + (tid >> 5);
    int col = (tid & 31) * 4;
    *(float4*)(obase + row * 128 + col) = *(const float4*)&comb[row][col];
  }
}

extern "C" void kernel_launch(void* const* d_in, const int* in_sizes, int n_in,
                              void* d_out, int out_size, void* d_ws, size_t ws_size,
                              hipStream_t stream){
  const float* x  = (const float*)d_in[0];
  // d_in[1] = mask : causal tril by construction, applied structurally
  const float* Wk = (const float*)d_in[2];
  const float* Wq = (const float*)d_in[3];
  const float* Wv = (const float*)d_in[4];
  char* ws = (char*)d_ws;
  unsigned short* Wt = (unsigned short*)(ws);                    // 768 KB
  unsigned short* Qb = (unsigned short*)(ws + (1ull  << 20));    // 8 MB
  unsigned short* Kb = (unsigned short*)(ws + (9ull  << 20));    // 8 MB
  unsigned short* Vt = (unsigned short*)(ws + (17ull << 20));    // 8 MB
  float* out = (float*)d_out;

  hipLaunchKernelGGL(prep_w,    dim3(1536), dim3(256), 0, stream, Wk, Wq, Wv, Wt);
  hipLaunchKernelGGL(proj_gemm, dim3(1024), dim3(256), 0, stream, x, Wt, Qb, Kb, Vt);
  hipLaunchKernelGGL(attn,      dim3(1024), dim3(256), 0, stream, Qb, Kb, Vt, out);
}

// Round 7
// 89.429 us; speedup vs baseline: 1.6648x; 1.6648x over previous
//
#include <hip/hip_runtime.h>
#include <hip/hip_bf16.h>
#include <stdint.h>

// B=16, T=2048, E=1024, H=128
typedef __attribute__((ext_vector_type(8))) short bf16x8;
typedef __attribute__((ext_vector_type(16))) float f32x16;
typedef __attribute__((ext_vector_type(4))) float f32x4;

__device__ __forceinline__ uint32_t cvt_pk_bf16(float a, float b){
  uint32_t r;
  asm volatile("v_cvt_pk_bf16_f32 %0, %1, %2" : "=v"(r) : "v"(a), "v"(b));
  return r;
}
__device__ __forceinline__ void permswap32(uint32_t &a, uint32_t &b){
  asm volatile("v_permlane32_swap_b32 %0, %1" : "+v"(a), "+v"(b));
}
__device__ __forceinline__ unsigned short f2bf(float f){
  uint32_t u = __float_as_uint(f);
  u += 0x7fff + ((u >> 16) & 1);   // RNE
  return (unsigned short)(u >> 16);
}
__device__ __forceinline__ void gload16(const void* g, void* l){
  __builtin_amdgcn_global_load_lds((const __attribute__((address_space(1))) void*)g,
                                   (__attribute__((address_space(3))) void*)l, 16, 0, 0);
}

// Layouts:
//  Wt lane-linear fragment-major: frag = (k>>5)*24 + (n>>4) (n=mat*128+h, k=e).
//    interior: elem(n,k) at lane*8 + (k&7), lane = (n&15) + (((k&31)>>3)<<4).
//    => a wave ds_read at lane*16B yields exactly the 16x16x32 B-fragment.
//  QK: elem(b,t,h) -> (b*64 + t/32)*4096 + (h/16)*512 + (t%32)*16 + (h%16)
//  V : elem(b,s,h) -> ((b*64 + s/32)*4 + h/32)*1024 + ((s/16)%2)*512 + (h%32)*16 + (s%16)

// ---------------- Kernel 1: W -> Wt bf16 lane-linear fragment-major
__global__ void prep_w(const float* __restrict__ Wk, const float* __restrict__ Wq,
                       const float* __restrict__ Wv, unsigned short* __restrict__ Wt){
  int idx = blockIdx.x * 256 + threadIdx.x;       // 0 .. 393215  (= dest address)
  int frag = idx >> 9;         // 0..767 = kq*24 + nq
  int r    = idx & 511;
  int ln   = r >> 3;           // lane 0..63
  int j    = r & 7;
  int kq = frag / 24;          // 0..31
  int nq = frag - kq * 24;     // 0..23
  int n  = nq * 16 + (ln & 15);          // 0..383
  int e  = kq * 32 + (ln >> 4) * 8 + j;  // 0..1023
  int mat = n >> 7;
  int h   = n & 127;
  const float* src = (mat == 0) ? Wq : (mat == 1) ? Wk : Wv;
  float v = src[e * 128 + h];
  if (mat == 0) v *= (1.4426950408889634f * 0.08838834764831845f); // log2e/sqrt(128)
  Wt[idx] = f2bf(v);
}

// ---------------- Kernel 2: fused QKV projection GEMM, async-staged (m201-style).
// BM=64, BN=384, BK=32. A (x, f32) triple-buffered via global_load_lds (2 steps ahead);
// B (Wt, bf16) double-buffered via global_load_lds (1 step ahead). Raw s_barrier +
// counted vmcnt(2) -- A(k+2) stays in flight across the barrier. Lane-linear LDS:
// all ds_reads are lane*16B contiguous, zero bank conflicts.
__global__ __launch_bounds__(256, 2) void proj_gemm(
    const float* __restrict__ x, const unsigned short* __restrict__ Wt,
    unsigned short* __restrict__ Qb, unsigned short* __restrict__ Kb,
    unsigned short* __restrict__ Vt){
  __shared__ __align__(16) float          As[3][2048];   // 3 x 8KB (64 rows x 32 f32, lane-order frags)
  __shared__ __align__(16) unsigned short Bs[2][12288];  // 2 x 24KB (24 frags x 512 bf16)

  const int tid  = threadIdx.x;
  const int lane = tid & 63;
  const int w    = tid >> 6;        // wave 0..3
  const int m0   = blockIdx.x * 64; // token-tile base (flat M=32768)

  f32x4 acc[4][6];
  #pragma unroll
  for (int i = 0; i < 4; ++i)
    #pragma unroll
    for (int jj = 0; jj < 6; ++jj) acc[i][jj] = (f32x4){0.f, 0.f, 0.f, 0.f};

  // A staging geometry: wave w stages frag am=w as two 1KB chunks (i=0,1).
  // chunk c=2w+i; lane_t = i*32 + (lane>>1); row = w*16 + (lane_t&15);
  // kk = (lane_t>>4)*8 + (lane&1)*4  -> 16B (4 f32) per lane.
  const int lt0 = (lane >> 1), lt1 = 32 + (lane >> 1);
  const int arow0 = w * 16 + (lt0 & 15), akk0 = (lt0 >> 4) * 8 + (lane & 1) * 4;
  const int arow1 = w * 16 + (lt1 & 15), akk1 = (lt1 >> 4) * 8 + (lane & 1) * 4;
  const float* asrc0 = x + (size_t)(m0 + arow0) * 1024 + akk0;
  const float* asrc1 = x + (size_t)(m0 + arow1) * 1024 + akk1;
  // B staging: wave w stages frags w*6..w*6+5; lane contributes 16B at lane*8 elems.
  const unsigned short* bsrc = Wt + (size_t)lane * 8;

  #define STAGE_A(kt, buf) {                                              \
    gload16(asrc0 + (kt) * 32, &As[buf][(2 * w + 0) * 256]);              \
    gload16(asrc1 + (kt) * 32, &As[buf][(2 * w + 1) * 256]);              \
  }
  #define STAGE_B(kt, buf) {                                              \
    _Pragma("unroll")                                                     \
    for (int jf = 0; jf < 6; ++jf){                                       \
      int f = w * 6 + jf;                                                 \
      gload16(bsrc + ((size_t)(kt) * 24 + f) * 512, &Bs[buf][f * 512]);   \
    }                                                                     \
  }

  union BU { uint32_t u[4]; bf16x8 v; };

  // prologue: B(0), A(0), A(1); wait all but newest 2 (A(1) stays in flight)
  STAGE_B(0, 0);
  STAGE_A(0, 0);
  STAGE_A(1, 1);
  asm volatile("s_waitcnt vmcnt(2)" ::: "memory");
  __builtin_amdgcn_s_barrier();
  __builtin_amdgcn_sched_barrier(0);

  for (int ks = 0; ks < 32; ++ks){
    const int bcur = ks & 1, bnxt = bcur ^ 1;
    const int acur = ks % 3, anxt2 = (ks + 2) % 3;
    const int kb = (ks + 1 < 32) ? ks + 1 : 31;
    const int ka = (ks + 2 < 32) ? ks + 2 : 31;
    // issue next-tile stages first: B(k+1) then A(k+2) (order matters for vmcnt)
    STAGE_B(kb, bnxt);
    STAGE_A(ka, anxt2);
    // fragment reads (conflict-free lane-linear)
    bf16x8 af[4];
    #pragma unroll
    for (int am = 0; am < 4; ++am){
      float4 lo = *(const float4*)&As[acur][am * 512 + lane * 8];
      float4 hi = *(const float4*)&As[acur][am * 512 + lane * 8 + 4];
      BU u; u.u[0] = cvt_pk_bf16(lo.x, lo.y); u.u[1] = cvt_pk_bf16(lo.z, lo.w);
            u.u[2] = cvt_pk_bf16(hi.x, hi.y); u.u[3] = cvt_pk_bf16(hi.z, hi.w);
      af[am] = u.v;
    }
    bf16x8 bf[6];
    #pragma unroll
    for (int bn = 0; bn < 6; ++bn)
      bf[bn] = *(const bf16x8*)&Bs[bcur][(w * 6 + bn) * 512 + lane * 8];
    __builtin_amdgcn_s_setprio(1);
    #pragma unroll
    for (int am = 0; am < 4; ++am)
      #pragma unroll
      for (int bn = 0; bn < 6; ++bn)
        acc[am][bn] = __builtin_amdgcn_mfma_f32_16x16x32_bf16(af[am], bf[bn], acc[am][bn], 0, 0, 0);
    __builtin_amdgcn_s_setprio(0);
    // retire A(k+1)+B(k+1); keep A(k+2) in flight across the barrier
    asm volatile("s_waitcnt vmcnt(2)" ::: "memory");
    __builtin_amdgcn_s_barrier();
    __builtin_amdgcn_sched_barrier(0);
  }

  const int b  = m0 >> 11;
  const int t0 = m0 & 2047;
  const int lr = lane & 15;
  const int lk = lane >> 4;
  #pragma unroll
  for (int am = 0; am < 4; ++am){
    #pragma unroll
    for (int bn = 0; bn < 6; ++bn){
      int c0   = w * 96 + bn * 16;
      int mat  = c0 >> 7;
      int hcol = (c0 & 127) + lr;
      int tr   = t0 + am * 16 + lk * 4;    // D: row=(lane>>4)*4+j, col=lane&15
      f32x4 v = acc[am][bn];
      if (mat <= 1){
        unsigned short* dst = (mat == 0) ? Qb : Kb;
        size_t base = (size_t)(b * 64 + (tr >> 5)) * 4096 + (size_t)(hcol >> 4) * 512 + (hcol & 15);
        #pragma unroll
        for (int jj = 0; jj < 4; ++jj)
          dst[base + (size_t)((tr + jj) & 31) * 16] = f2bf(v[jj]);
      } else { // V fragment-major: 4 consecutive s -> 8B store
        ushort4 pk;
        pk.x = f2bf(v[0]); pk.y = f2bf(v[1]); pk.z = f2bf(v[2]); pk.w = f2bf(v[3]);
        size_t addr = (size_t)((b * 64 + (tr >> 5)) * 4 + (hcol >> 5)) * 1024
                    + (size_t)((tr >> 4) & 1) * 512 + (size_t)(hcol & 31) * 16 + (tr & 15);
        *(ushort4*)(Vt + addr) = pk;
      }
    }
  }
  #undef STAGE_A
  #undef STAGE_B
}

// ---------------- Kernel 3: causal flash attention, swapped-QK 32x32x16.
// 1024 blocks, 4 waves = 4-way kv split, scale-then-sum combine (17.9KB LDS).
__global__ __launch_bounds__(256, 2) void attn(
    const unsigned short* __restrict__ Qf, const unsigned short* __restrict__ Kf,
    const unsigned short* __restrict__ Vf, float* __restrict__ out){
  __shared__ float comb[32][132];
  __shared__ float msh[4][32];
  __shared__ float lsh[4][32];

  const int tid  = threadIdx.x;
  const int lane = tid & 63;
  const int w    = tid >> 6;            // kv-split index 0..3
  const int bid  = blockIdx.x;
  const int xcd  = bid & 7;
  const int k    = bid >> 3;            // 0..127 within XCD
  const int a    = k & 31;
  const int mdx  = k >> 5;              // 0..3
  const int b    = xcd * 2 + (mdx >> 1);
  const int c    = (mdx & 1) ? a : 63 - a;   // per-CU sets {63-a, a} x 2 batches
  const int r0   = c * 32;
  const int q5   = lane & 31;
  const int hi   = lane >> 5;

  bf16x8 qf[8];
  const unsigned short* qp = Qf + (size_t)(b * 64 + c) * 4096 + q5 * 16 + hi * 8;
  #pragma unroll
  for (int f = 0; f < 8; ++f) qf[f] = *(const bf16x8*)(qp + f * 512);

  f32x16 oacc[4];
  #pragma unroll
  for (int i = 0; i < 4; ++i) oacc[i] = (f32x16)(0.f);
  float m = -1e30f, l = 0.f;

  const unsigned short* kb = Kf + (size_t)b * 64 * 4096;
  const unsigned short* vb = Vf + (size_t)b * 64 * 4096;

  bf16x8 kf[8];
  if (w <= c){
    const unsigned short* kp = kb + (size_t)w * 4096 + q5 * 16 + hi * 8;
    #pragma unroll
    for (int f = 0; f < 8; ++f) kf[f] = *(const bf16x8*)(kp + f * 512);
  }

  for (int t = w; t <= c; t += 4){
    f32x16 sacc = (f32x16)(0.f);   // S^T[s][q] = sum_h K[s][h] Q[q][h]
    #pragma unroll
    for (int f = 0; f < 8; ++f)
      sacc = __builtin_amdgcn_mfma_f32_32x32x16_bf16(kf[f], qf[f], sacc, 0, 0, 0);
    // prefetch next K tile (overlaps softmax+PV)
    if (t + 4 <= c){
      const unsigned short* kp = kb + (size_t)(t + 4) * 4096 + q5 * 16 + hi * 8;
      #pragma unroll
      for (int f = 0; f < 8; ++f) kf[f] = *(const bf16x8*)(kp + f * 512);
    }
    // V fragments (contiguous 1KB per instr), issued before softmax
    bf16x8 vf[8];
    const unsigned short* vp = vb + (size_t)t * 4096 + q5 * 16 + hi * 8;
    #pragma unroll
    for (int ht = 0; ht < 4; ++ht)
      #pragma unroll
      for (int sf = 0; sf < 2; ++sf)
        vf[ht * 2 + sf] = *(const bf16x8*)(vp + ht * 1024 + sf * 512);

    float sv[16];
    #pragma unroll
    for (int r = 0; r < 16; ++r) sv[r] = sacc[r];
    if (t == c){   // diagonal tile: mask s>q  (row = (r&3)+8*(r>>2)+4*hi, col q = q5)
      #pragma unroll
      for (int r = 0; r < 16; ++r){
        int srow = (r & 3) + 8 * (r >> 2) + 4 * hi;
        if (srow > q5) sv[r] = -1e30f;
      }
    }
    float pm = sv[0];
    #pragma unroll
    for (int r = 1; r < 16; ++r) pm = fmaxf(pm, sv[r]);
    pm = fmaxf(pm, __shfl_xor(pm, 32));
    if (!__all(pm - m <= 8.0f)){   // defer-max (log2 domain)
      float mn = fmaxf(m, pm);
      float al = exp2f(m - mn);
      #pragma unroll
      for (int i = 0; i < 4; ++i) oacc[i] *= al;
      l *= al;
      m = mn;
    }
    float pv[16]; float ts = 0.f;
    #pragma unroll
    for (int r = 0; r < 16; ++r){ pv[r] = exp2f(sv[r] - m); ts += pv[r]; }
    ts += __shfl_xor(ts, 32);
    l += ts;
    // P^T -> bf16 B-frags: cvt_pk + permlane32_swap (fills both k-halves)
    uint32_t w0 = cvt_pk_bf16(pv[0],  pv[1]);
    uint32_t w2 = cvt_pk_bf16(pv[4],  pv[5]);  permswap32(w0, w2);
    uint32_t w1 = cvt_pk_bf16(pv[2],  pv[3]);
    uint32_t w3 = cvt_pk_bf16(pv[6],  pv[7]);  permswap32(w1, w3);
    uint32_t w4 = cvt_pk_bf16(pv[8],  pv[9]);
    uint32_t w6 = cvt_pk_bf16(pv[12], pv[13]); permswap32(w4, w6);
    uint32_t w5 = cvt_pk_bf16(pv[10], pv[11]);
    uint32_t w7 = cvt_pk_bf16(pv[14], pv[15]); permswap32(w5, w7);
    union { uint32_t u[4]; bf16x8 v; } pf0u, pf1u;
    pf0u.u[0] = w0; pf0u.u[1] = w1; pf0u.u[2] = w2; pf0u.u[3] = w3;
    pf1u.u[0] = w4; pf1u.u[1] = w5; pf1u.u[2] = w6; pf1u.u[3] = w7;
    #pragma unroll
    for (int ht = 0; ht < 4; ++ht){   // O^T[h][q] += V^T · P^T
      oacc[ht] = __builtin_amdgcn_mfma_f32_32x32x16_bf16(vf[ht * 2 + 0], pf0u.v, oacc[ht], 0, 0, 0);
      oacc[ht] = __builtin_amdgcn_mfma_f32_32x32x16_bf16(vf[ht * 2 + 1], pf1u.v, oacc[ht], 0, 0, 0);
    }
  }

  // -------- scale-then-sum combine --------
  if (hi == 0){ msh[w][q5] = m; lsh[w][q5] = l; }
  __syncthreads();
  {
    float mv0 = msh[0][q5], mv1 = msh[1][q5], mv2 = msh[2][q5], mv3 = msh[3][q5];
    float lv0 = lsh[0][q5], lv1 = lsh[1][q5], lv2 = lsh[2][q5], lv3 = lsh[3][q5];
    float mfm = fmaxf(fmaxf(mv0, mv1), fmaxf(mv2, mv3));
    float lf  = lv0 * exp2f(mv0 - mfm) + lv1 * exp2f(mv1 - mfm)
              + lv2 * exp2f(mv2 - mfm) + lv3 * exp2f(mv3 - mfm);
    float s = exp2f(m - mfm) / lf;
    #pragma unroll
    for (int ht = 0; ht < 4; ++ht) oacc[ht] *= s;
  }
  // serial RMW accumulate into comb (wave 0 writes, 1..3 add)
  #pragma unroll 1
  for (int rr = 0; rr < 4; ++rr){
    if (w == rr){
      #pragma unroll
      for (int ht = 0; ht < 4; ++ht)
        #pragma unroll
        for (int r4 = 0; r4 < 4; ++r4){
          int hh = ht * 32 + 8 * r4 + 4 * hi;
          float4 add;
          add.x = oacc[ht][r4 * 4 + 0]; add.y = oacc[ht][r4 * 4 + 1];
          add.z = oacc[ht][r4 * 4 + 2]; add.w = oacc[ht][r4 * 4 + 3];
          float* p = &comb[q5][hh];
          if (rr == 0) *(float4*)p = add;
          else { float4 cur = *(const float4*)p;
                 cur.x += add.x; cur.y += add.y; cur.z += add.z; cur.w += add.w;
                 *(float4*)p = cur; }
        }
    }
    __syncthreads();
  }
  // cooperative coalesced store: 32 rows x 128 f32
  float* obase = out + ((size_t)b * 2048 + r0) * 128;
  #pragma unroll
  for (int it = 0; it < 4; ++it){
    int row = it * 8 + (tid >> 5);
    int col = (tid & 31) * 4;
    *(float4*)(obase + row * 128 + col) = *(const float4*)&comb[row][col];
  }
}

extern "C" void kernel_launch(void* const* d_in, const int* in_sizes, int n_in,
                              void* d_out, int out_size, void* d_ws, size_t ws_size,
                              hipStream_t stream){
  const float* x  = (const float*)d_in[0];
  // d_in[1] = mask : causal tril by construction, applied structurally
  const float* Wk = (const float*)d_in[2];
  const float* Wq = (const float*)d_in[3];
  const float* Wv = (const float*)d_in[4];
  char* ws = (char*)d_ws;
  unsigned short* Wt = (unsigned short*)(ws);                    // 768 KB
  unsigned short* Qb = (unsigned short*)(ws + (1ull  << 20));    // 8 MB
  unsigned short* Kb = (unsigned short*)(ws + (9ull  << 20));    // 8 MB
  unsigned short* Vt = (unsigned short*)(ws + (17ull << 20));    // 8 MB
  float* out = (float*)d_out;

  hipLaunchKernelGGL(prep_w,    dim3(1536), dim3(256), 0, stream, Wk, Wq, Wv, Wt);
  hipLaunchKernelGGL(proj_gemm, dim3(512),  dim3(256), 0, stream, x, Wt, Qb, Kb, Vt);
  hipLaunchKernelGGL(attn,      dim3(1024), dim3(256), 0, stream, Qb, Kb, Vt, out);
}